// Round 19
// baseline (63.907 us; speedup 1.0000x reference)
//
#include <hip/hip_runtime.h>
#include <math.h>

#define NB   4
#define CIN  512
#define HID  64
#define NK   11     // NUM_CLASSES+1
#define HH1  60
#define W1p  80
#define P1   4800
#define HH2  30
#define W2p  40
#define P2   1200
#define HO   480
#define WOp  640
#define NP1  (NB*P1)    // 19200
#define NP2  (NB*P2)    // 4800
#define PLANE ((size_t)HO*WOp)                  // 307200
#define SEG_OFF ((size_t)NB*NK*PLANE)           // 13,516,800
#define BBX_OFF (SEG_OFF + (size_t)NB*PLANE)    // 14,745,600

// ws layout in floats. Packed bf16 W-fragments: 131072 ushort = 65536 floats.
#define WS_C1  65536                            // 19200*64 = 1,228,800
#define WS_F2  (WS_C1 + NP1*64)                 // 4800*64  =   307,200
#define WS_SEG (WS_F2 + NP2*64)                 // 19200 ints

typedef __attribute__((ext_vector_type(8))) short bf16x8;
typedef __attribute__((ext_vector_type(4))) float f32x4;

// RNE fp32 -> bf16, returns bits, writes residual x - bf16(x)
__device__ __forceinline__ unsigned short bfsplit(float x, float& resid) {
    unsigned u = __float_as_uint(x);
    unsigned t = u + 0x7FFFu + ((u >> 16) & 1u);
    unsigned short h = (unsigned short)(t >> 16);
    resid = x - __uint_as_float((unsigned)h << 16);
    return h;
}

// async global->LDS DMA, 16B per lane: lds dest = uniform base + lane*16
__device__ __forceinline__ void gld16(const void* g, void* l) {
    __builtin_amdgcn_global_load_lds(
        (const __attribute__((address_space(1))) void*)g,
        (__attribute__((address_space(3))) void*)l, 16, 0, 0);
}

// -------- pack weights into chunk-major A-fragment pages, 2-plane split -----
// (identical to r13/r18, end-to-end verified at absmax 3.9e-3)
__global__ __launch_bounds__(256) void pack_w(const float* __restrict__ w1,
                                              const float* __restrict__ w2,
                                              float* __restrict__ ws) {
    int i = blockIdx.x * 256 + threadIdx.x;   // 0..32767
    if (i >= HID * CIN) return;
    int o = i >> 9, c = i & 511;
    int chunk = c >> 6, r = c & 63, ks2 = r >> 5, k = r & 31;
    int lane = (o & 15) + ((k >> 3) << 4);
    int mt = o >> 4;
    int d = ((((chunk * 2 + ks2) * 4 + mt) * 2) * 64 + lane) * 8 + (k & 7);
    unsigned short* q = (unsigned short*)ws;
    float r1;
    unsigned short h = bfsplit(w1[i], r1);
    unsigned short m = bfsplit(r1, r1);
    q[d] = h; q[d + 512] = m;                 // plane stride = 64*8 = 512
    h = bfsplit(w2[i], r1); m = bfsplit(r1, r1);
    q[65536 + d] = h; q[65536 + d + 512] = m;
}

// -------- conv1x1 via MFMA v18 (FROZEN): async DMA staging ------------------
// Verified r18: 66.9 -> 55.7us total. X and A staged via global_load_lds 16B
// DMA (unsinkable, zero VGPRs); per chunk: {issue DMA c+1 | convert | lgkm+
// s_barrier (DMA in flight) | MFMA | __syncthreads (drains DMA c+1)}.
__global__ __launch_bounds__(256) void conv_mfma(const float* __restrict__ f1,
                                                 const float* __restrict__ f2,
                                                 const float* __restrict__ b1v,
                                                 const float* __restrict__ b2v,
                                                 const float* __restrict__ wsbase,
                                                 float* __restrict__ c1o,
                                                 float* __restrict__ f2o) {
    __shared__ float xraw[2][4096];   // [buf][ch64][px64] fp32, 16KB each
    __shared__ int   alds[2][4096];   // [buf][linear A-frag page], 16KB each
    __shared__ int   xpl[4096];       // B-frags [pt4][ks2 2][plane2][lane64][w4]
    int t = blockIdx.x;
    const float* X; const float* bias; float* Cout; const int* WPK;
    int P, px0;
    const unsigned short* q = (const unsigned short*)wsbase;
    if (t < 300) {
        int b = t / 75, ti = t % 75;
        px0 = ti * 64;
        X = f1 + (size_t)b * CIN * P1;  P = P1;  bias = b1v;
        WPK = (const int*)q;
        Cout = c1o + (size_t)b * P1 * 64;
    } else {
        int u = t - 300; int b = u / 19, ti = u % 19;
        px0 = ti * 64; if (px0 > P2 - 64) px0 = P2 - 64;  // tail overlap benign
        X = f2 + (size_t)b * CIN * P2;  P = P2;  bias = b2v;
        WPK = (const int*)(q + 65536);
        Cout = f2o + (size_t)b * P2 * 64;
    }
    int tid  = threadIdx.x;
    int lane = tid & 63;
    int wv   = tid >> 6;              // staging pt AND compute mt
    int pcol = lane & 15, kgrp = lane >> 4;

    auto dmaX = [&](int cc, int buf) {
#pragma unroll
        for (int qq = 0; qq < 4; ++qq) {
            int k = wv * 4 + qq;
            const float* g = X + (size_t)(cc * 64 + k * 4 + (lane >> 4)) * P
                           + px0 + (lane & 15) * 4;
            gld16(g, (void*)&xraw[buf][k * 256]);
        }
    };
    auto dmaA = [&](int cc, int buf) {
#pragma unroll
        for (int qq = 0; qq < 4; ++qq) {
            int k = wv * 4 + qq;
            const int* g = WPK + cc * 4096 + k * 256 + lane * 4;
            gld16(g, (void*)&alds[buf][k * 256]);
        }
    };
    auto convert = [&](int buf) {
        int pxl = wv * 16 + pcol;
#pragma unroll
        for (int ks2 = 0; ks2 < 2; ++ks2) {
            int hh[8], mm[8];
#pragma unroll
            for (int j = 0; j < 8; ++j) {
                float x = xraw[buf][(ks2 * 32 + kgrp * 8 + j) * 64 + pxl];
                float r;
                unsigned short h = bfsplit(x, r);
                unsigned short m = bfsplit(r, r);
                hh[j] = h; mm[j] = m;
            }
            int4 H, M;
            ((int*)&H)[0] = hh[0] | (hh[1] << 16); ((int*)&H)[1] = hh[2] | (hh[3] << 16);
            ((int*)&H)[2] = hh[4] | (hh[5] << 16); ((int*)&H)[3] = hh[6] | (hh[7] << 16);
            ((int*)&M)[0] = mm[0] | (mm[1] << 16); ((int*)&M)[1] = mm[2] | (mm[3] << 16);
            ((int*)&M)[2] = mm[4] | (mm[5] << 16); ((int*)&M)[3] = mm[6] | (mm[7] << 16);
            int pg = ((wv * 2 + ks2) * 2) * 256 + lane * 4;
            *(int4*)&xpl[pg]       = H;
            *(int4*)&xpl[pg + 256] = M;
        }
    };

    union FU { int4 q; bf16x8 v; };
    f32x4 acc[4];
#pragma unroll
    for (int st = 0; st < 4; ++st) acc[st] = (f32x4){0.f, 0.f, 0.f, 0.f};

    dmaX(0, 0); dmaA(0, 0);
    __syncthreads();

    int cur = 0;
    for (int c = 0; c < 8; ++c) {
        if (c < 7) { dmaX(c + 1, cur ^ 1); dmaA(c + 1, cur ^ 1); }
        convert(cur);
        asm volatile("s_waitcnt lgkmcnt(0)" ::: "memory");
        __builtin_amdgcn_s_barrier();
        __builtin_amdgcn_sched_barrier(0);
#pragma unroll
        for (int ks2 = 0; ks2 < 2; ++ks2) {
            FU Ah, Am;
            int pa = ((ks2 * 4 + wv) * 2) * 256 + lane * 4;
            Ah.q = *(const int4*)&alds[cur][pa];
            Am.q = *(const int4*)&alds[cur][pa + 256];
#pragma unroll
            for (int st = 0; st < 4; ++st) {
                FU Bh, Bm;
                int pb = ((st * 2 + ks2) * 2) * 256 + lane * 4;
                Bh.q = *(const int4*)&xpl[pb];
                Bm.q = *(const int4*)&xpl[pb + 256];
                acc[st] = __builtin_amdgcn_mfma_f32_16x16x32_bf16(Ah.v, Bh.v, acc[st], 0, 0, 0);
                acc[st] = __builtin_amdgcn_mfma_f32_16x16x32_bf16(Ah.v, Bm.v, acc[st], 0, 0, 0);
                acc[st] = __builtin_amdgcn_mfma_f32_16x16x32_bf16(Am.v, Bh.v, acc[st], 0, 0, 0);
                acc[st] = __builtin_amdgcn_mfma_f32_16x16x32_bf16(Am.v, Bm.v, acc[st], 0, 0, 0);
            }
        }
        __builtin_amdgcn_sched_barrier(0);
        __syncthreads();    // drains vmcnt (DMA c+1 landed) + lgkm, barrier
        cur ^= 1;
    }

    int r4 = (lane >> 4) * 4;
    float4 bb = *(const float4*)(bias + wv * 16 + r4);
#pragma unroll
    for (int st = 0; st < 4; ++st) {
        int px = px0 + st * 16 + pcol;
        float a0 = acc[st][0] + bb.x;
        float a1 = acc[st][1] + bb.y;
        float a2 = acc[st][2] + bb.z;
        float a3 = acc[st][3] + bb.w;
        *(float4*)(Cout + (size_t)px * 64 + wv * 16 + r4) =
            make_float4(a0 > 0.f ? a0 : 0.f, a1 > 0.f ? a1 : 0.f,
                        a2 > 0.f ? a2 : 0.f, a3 > 0.f ? a3 : 0.f);
    }
}

// -------- up_head: fused head + 8x upsample stores --------------------------
// 300 blocks x 1024 thr (4.7 waves/SIMD vs head_kernel's 0.3). Per block:
// 64-px tile -> head on 64 lanes (c1/f2 reads are L2-hot) -> prob/seg in LDS
// -> 12K float4 replicated stores (r15-verified store loop). Removes the
// low-occupancy head dispatch + the 1.2MB prb round-trip + one launch.
__global__ __launch_bounds__(1024) void up_head(const float* __restrict__ wo,
                                                const float* __restrict__ bo,
                                                float* __restrict__ ws,
                                                float* __restrict__ out) {
    __shared__ float prob[64 * 13];
    __shared__ float swo[NK * 64];
    __shared__ float sbo[NK];
    int t = blockIdx.x;            // 0..299
    int b = t / 75, ti = t % 75;
    int px0 = ti * 64;
    int tid = threadIdx.x;
    for (int i = tid; i < NK * 64; i += 1024) swo[i] = wo[i];
    if (tid < NK) sbo[tid] = bo[tid];
    __syncthreads();

    if (tid < 64) {
        int px_g = px0 + tid;
        int y = px_g / W1p, x = px_g % W1p;
        int qp = (y >> 1) * W2p + (x >> 1);
        const float* c1p = ws + WS_C1 + ((size_t)b * P1 + px_g) * 64;
        const float* f2p = ws + WS_F2 + ((size_t)b * P2 + qp) * 64;
        float ok[NK];
#pragma unroll
        for (int k = 0; k < NK; ++k) ok[k] = sbo[k];
#pragma unroll
        for (int o4 = 0; o4 < 16; ++o4) {
            float4 cq = *(const float4*)(c1p + o4 * 4);
            float4 fq = *(const float4*)(f2p + o4 * 4);
            float co[4] = { cq.x + fq.x, cq.y + fq.y, cq.z + fq.z, cq.w + fq.w };
#pragma unroll
            for (int j = 0; j < 4; ++j) {
                int o = o4 * 4 + j;
#pragma unroll
                for (int k = 0; k < NK; ++k) ok[k] = fmaf(co[j], swo[k * 64 + o], ok[k]);
            }
        }
        float m = 0.f;
#pragma unroll
        for (int k = 0; k < NK; ++k) {
            ok[k] = ok[k] > 0.f ? ok[k] : 0.f;
            if (ok[k] > m) m = ok[k];
        }
        float e[NK], sum = 0.f;
#pragma unroll
        for (int k = 0; k < NK; ++k) { e[k] = expf(ok[k] - m); sum += e[k]; }
        float inv = 1.f / sum;
        int arg = 0; float best = ok[0];
#pragma unroll
        for (int k = 1; k < NK; ++k) { if (ok[k] > best) { best = ok[k]; arg = k; } }
#pragma unroll
        for (int k = 0; k < NK; ++k) prob[tid * 13 + k] = e[k] * inv;
        prob[tid * 13 + 11] = (float)arg;
        ((int*)(ws + WS_SEG))[b * P1 + px_g] = arg;
    }
    __syncthreads();

    // 12 planes (11 prob + seg) x 8 dy x 64 px x 2 float4 = 12288 stores
    for (int id = tid; id < 12 * 8 * 128; id += 1024) {
        int k   = id >> 10;
        int rem = id & 1023;
        int dy  = rem >> 7;
        int g   = rem & 127;
        int j   = g >> 1;
        int qq  = g & 1;
        int px_g = px0 + j;
        int y = px_g / W1p, x = px_g % W1p;
        float v = prob[j * 13 + k];
        size_t base;
        if (k < NK)
            base = (((size_t)(b * NK + k) * HO) + (size_t)(y * 8 + dy)) * WOp + x * 8 + qq * 4;
        else
            base = SEG_OFF + (((size_t)b * HO) + (size_t)(y * 8 + dy)) * WOp + x * 8 + qq * 4;
        *(float4*)(out + base) = make_float4(v, v, v, v);
    }
}

// ---------------- bbox: per-(batch,class) min/max/count over 60x80 seg ------
__global__ __launch_bounds__(256) void bbx_kernel(const float* __restrict__ ws,
                                                  float* __restrict__ out) {
    __shared__ int cnt[10], xmn[10], xmx[10], ymn[10], ymx[10];
    int b = blockIdx.x;
    int t = threadIdx.x;
    if (t < 10) { cnt[t] = 0; xmn[t] = 1 << 30; xmx[t] = -1; ymn[t] = 1 << 30; ymx[t] = -1; }
    __syncthreads();
    const int* seg = (const int*)(ws + WS_SEG) + b * P1;
    for (int p = t; p < P1; p += 256) {
        int s = seg[p];
        if (s >= 1 && s <= 9) {
            int y = p / W1p, x = p % W1p;
            atomicAdd(&cnt[s], 1);
            atomicMin(&xmn[s], x); atomicMax(&xmx[s], x);
            atomicMin(&ymn[s], y); atomicMax(&ymx[s], y);
        }
    }
    __syncthreads();
    if (t < 9) {
        int c = t + 1;
        bool valid = cnt[c] * 64 >= 500;    // upsampled count = 64*count
        float r[6];
        if (valid) {
            r[0] = (float)b;
            r[1] = (float)(xmn[c] * 8);
            r[2] = (float)(ymn[c] * 8);
            r[3] = (float)(xmx[c] * 8 + 7);
            r[4] = (float)(ymx[c] * 8 + 7);
            r[5] = (float)c;
        } else {
            for (int i = 0; i < 6; ++i) r[i] = -1.f;
        }
        float* row = out + BBX_OFF + (size_t)(b * 9 + t) * 6;
        for (int i = 0; i < 6; ++i) row[i] = r[i];
    }
}

extern "C" void kernel_launch(void* const* d_in, const int* in_sizes, int n_in,
                              void* d_out, int out_size, void* d_ws, size_t ws_size,
                              hipStream_t stream) {
    const float* f1 = (const float*)d_in[0];
    const float* f2 = (const float*)d_in[1];
    const float* w1 = (const float*)d_in[2];
    const float* b1 = (const float*)d_in[3];
    const float* w2 = (const float*)d_in[4];
    const float* b2 = (const float*)d_in[5];
    const float* wo = (const float*)d_in[6];
    const float* bo = (const float*)d_in[7];
    float* ws  = (float*)d_ws;
    float* out = (float*)d_out;

    pack_w<<<128, 256, 0, stream>>>(w1, w2, ws);
    conv_mfma<<<376, 256, 0, stream>>>(f1, f2, b1, b2, ws,
                                       ws + WS_C1, ws + WS_F2);
    up_head<<<300, 1024, 0, stream>>>(wo, bo, ws, out);
    bbx_kernel<<<NB, 256, 0, stream>>>(ws, out);
}

// Round 20
// 57.783 us; speedup vs baseline: 1.1060x; 1.1060x over previous
//
#include <hip/hip_runtime.h>
#include <math.h>

#define NB   4
#define CIN  512
#define HID  64
#define NK   11     // NUM_CLASSES+1
#define HH1  60
#define W1p  80
#define P1   4800
#define HH2  30
#define W2p  40
#define P2   1200
#define HO   480
#define WOp  640
#define NP1  (NB*P1)    // 19200
#define NP2  (NB*P2)    // 4800
#define PLANE ((size_t)HO*WOp)                  // 307200
#define SEG_OFF ((size_t)NB*NK*PLANE)           // 13,516,800
#define BBX_OFF (SEG_OFF + (size_t)NB*PLANE)    // 14,745,600

// ws layout in floats. Packed bf16 W-fragments: 131072 ushort = 65536 floats.
#define WS_C1  65536                            // 19200*64 = 1,228,800
#define WS_F2  (WS_C1 + NP1*64)                 // 4800*64  =   307,200
#define WS_PRB (WS_F2 + NP2*64)                 // 19200*12 =   230,400
#define WS_SEG (WS_PRB + NP1*12)                // 19200 ints

typedef __attribute__((ext_vector_type(8))) short bf16x8;
typedef __attribute__((ext_vector_type(4))) float f32x4;

// RNE fp32 -> bf16, returns bits, writes residual x - bf16(x)
__device__ __forceinline__ unsigned short bfsplit(float x, float& resid) {
    unsigned u = __float_as_uint(x);
    unsigned t = u + 0x7FFFu + ((u >> 16) & 1u);
    unsigned short h = (unsigned short)(t >> 16);
    resid = x - __uint_as_float((unsigned)h << 16);
    return h;
}

// async global->LDS DMA, 16B per lane: lds dest = uniform base + lane*16
__device__ __forceinline__ void gld16(const void* g, void* l) {
    __builtin_amdgcn_global_load_lds(
        (const __attribute__((address_space(1))) void*)g,
        (__attribute__((address_space(3))) void*)l, 16, 0, 0);
}

// -------- pack weights into chunk-major A-fragment pages, 2-plane split -----
// (identical to r13/r18, end-to-end verified at absmax 3.9e-3)
__global__ __launch_bounds__(256) void pack_w(const float* __restrict__ w1,
                                              const float* __restrict__ w2,
                                              float* __restrict__ ws) {
    int i = blockIdx.x * 256 + threadIdx.x;   // 0..32767
    if (i >= HID * CIN) return;
    int o = i >> 9, c = i & 511;
    int chunk = c >> 6, r = c & 63, ks2 = r >> 5, k = r & 31;
    int lane = (o & 15) + ((k >> 3) << 4);
    int mt = o >> 4;
    int d = ((((chunk * 2 + ks2) * 4 + mt) * 2) * 64 + lane) * 8 + (k & 7);
    unsigned short* q = (unsigned short*)ws;
    float r1;
    unsigned short h = bfsplit(w1[i], r1);
    unsigned short m = bfsplit(r1, r1);
    q[d] = h; q[d + 512] = m;                 // plane stride = 64*8 = 512
    h = bfsplit(w2[i], r1); m = bfsplit(r1, r1);
    q[65536 + d] = h; q[65536 + d + 512] = m;
}

// -------- conv1x1 via MFMA v18 (FROZEN): async DMA staging ------------------
// Verified r18: 66.9 -> 55.7us total. X and A staged via global_load_lds 16B
// DMA (unsinkable, zero VGPRs); per chunk: {issue DMA c+1 | convert | lgkm+
// s_barrier (DMA in flight) | MFMA | __syncthreads (drains DMA c+1)}.
__global__ __launch_bounds__(256) void conv_mfma(const float* __restrict__ f1,
                                                 const float* __restrict__ f2,
                                                 const float* __restrict__ b1v,
                                                 const float* __restrict__ b2v,
                                                 const float* __restrict__ wsbase,
                                                 float* __restrict__ c1o,
                                                 float* __restrict__ f2o) {
    __shared__ float xraw[2][4096];   // [buf][ch64][px64] fp32, 16KB each
    __shared__ int   alds[2][4096];   // [buf][linear A-frag page], 16KB each
    __shared__ int   xpl[4096];       // B-frags [pt4][ks2 2][plane2][lane64][w4]
    int t = blockIdx.x;
    const float* X; const float* bias; float* Cout; const int* WPK;
    int P, px0;
    const unsigned short* q = (const unsigned short*)wsbase;
    if (t < 300) {
        int b = t / 75, ti = t % 75;
        px0 = ti * 64;
        X = f1 + (size_t)b * CIN * P1;  P = P1;  bias = b1v;
        WPK = (const int*)q;
        Cout = c1o + (size_t)b * P1 * 64;
    } else {
        int u = t - 300; int b = u / 19, ti = u % 19;
        px0 = ti * 64; if (px0 > P2 - 64) px0 = P2 - 64;  // tail overlap benign
        X = f2 + (size_t)b * CIN * P2;  P = P2;  bias = b2v;
        WPK = (const int*)(q + 65536);
        Cout = f2o + (size_t)b * P2 * 64;
    }
    int tid  = threadIdx.x;
    int lane = tid & 63;
    int wv   = tid >> 6;              // staging pt AND compute mt
    int pcol = lane & 15, kgrp = lane >> 4;

    auto dmaX = [&](int cc, int buf) {
#pragma unroll
        for (int qq = 0; qq < 4; ++qq) {
            int k = wv * 4 + qq;
            const float* g = X + (size_t)(cc * 64 + k * 4 + (lane >> 4)) * P
                           + px0 + (lane & 15) * 4;
            gld16(g, (void*)&xraw[buf][k * 256]);
        }
    };
    auto dmaA = [&](int cc, int buf) {
#pragma unroll
        for (int qq = 0; qq < 4; ++qq) {
            int k = wv * 4 + qq;
            const int* g = WPK + cc * 4096 + k * 256 + lane * 4;
            gld16(g, (void*)&alds[buf][k * 256]);
        }
    };
    auto convert = [&](int buf) {
        int pxl = wv * 16 + pcol;
#pragma unroll
        for (int ks2 = 0; ks2 < 2; ++ks2) {
            int hh[8], mm[8];
#pragma unroll
            for (int j = 0; j < 8; ++j) {
                float x = xraw[buf][(ks2 * 32 + kgrp * 8 + j) * 64 + pxl];
                float r;
                unsigned short h = bfsplit(x, r);
                unsigned short m = bfsplit(r, r);
                hh[j] = h; mm[j] = m;
            }
            int4 H, M;
            ((int*)&H)[0] = hh[0] | (hh[1] << 16); ((int*)&H)[1] = hh[2] | (hh[3] << 16);
            ((int*)&H)[2] = hh[4] | (hh[5] << 16); ((int*)&H)[3] = hh[6] | (hh[7] << 16);
            ((int*)&M)[0] = mm[0] | (mm[1] << 16); ((int*)&M)[1] = mm[2] | (mm[3] << 16);
            ((int*)&M)[2] = mm[4] | (mm[5] << 16); ((int*)&M)[3] = mm[6] | (mm[7] << 16);
            int pg = ((wv * 2 + ks2) * 2) * 256 + lane * 4;
            *(int4*)&xpl[pg]       = H;
            *(int4*)&xpl[pg + 256] = M;
        }
    };

    union FU { int4 q; bf16x8 v; };
    f32x4 acc[4];
#pragma unroll
    for (int st = 0; st < 4; ++st) acc[st] = (f32x4){0.f, 0.f, 0.f, 0.f};

    dmaX(0, 0); dmaA(0, 0);
    __syncthreads();

    int cur = 0;
    for (int c = 0; c < 8; ++c) {
        if (c < 7) { dmaX(c + 1, cur ^ 1); dmaA(c + 1, cur ^ 1); }
        convert(cur);
        asm volatile("s_waitcnt lgkmcnt(0)" ::: "memory");
        __builtin_amdgcn_s_barrier();
        __builtin_amdgcn_sched_barrier(0);
#pragma unroll
        for (int ks2 = 0; ks2 < 2; ++ks2) {
            FU Ah, Am;
            int pa = ((ks2 * 4 + wv) * 2) * 256 + lane * 4;
            Ah.q = *(const int4*)&alds[cur][pa];
            Am.q = *(const int4*)&alds[cur][pa + 256];
#pragma unroll
            for (int st = 0; st < 4; ++st) {
                FU Bh, Bm;
                int pb = ((st * 2 + ks2) * 2) * 256 + lane * 4;
                Bh.q = *(const int4*)&xpl[pb];
                Bm.q = *(const int4*)&xpl[pb + 256];
                acc[st] = __builtin_amdgcn_mfma_f32_16x16x32_bf16(Ah.v, Bh.v, acc[st], 0, 0, 0);
                acc[st] = __builtin_amdgcn_mfma_f32_16x16x32_bf16(Ah.v, Bm.v, acc[st], 0, 0, 0);
                acc[st] = __builtin_amdgcn_mfma_f32_16x16x32_bf16(Am.v, Bh.v, acc[st], 0, 0, 0);
                acc[st] = __builtin_amdgcn_mfma_f32_16x16x32_bf16(Am.v, Bm.v, acc[st], 0, 0, 0);
            }
        }
        __builtin_amdgcn_sched_barrier(0);
        __syncthreads();    // drains vmcnt (DMA c+1 landed) + lgkm, barrier
        cur ^= 1;
    }

    int r4 = (lane >> 4) * 4;
    float4 bb = *(const float4*)(bias + wv * 16 + r4);
#pragma unroll
    for (int st = 0; st < 4; ++st) {
        int px = px0 + st * 16 + pcol;
        float a0 = acc[st][0] + bb.x;
        float a1 = acc[st][1] + bb.y;
        float a2 = acc[st][2] + bb.z;
        float a3 = acc[st][3] + bb.w;
        *(float4*)(Cout + (size_t)px * 64 + wv * 16 + r4) =
            make_float4(a0 > 0.f ? a0 : 0.f, a1 > 0.f ? a1 : 0.f,
                        a2 > 0.f ? a2 : 0.f, a3 > 0.f ? a3 : 0.f);
    }
}

// ---------------- head: add feat2-up, wo conv, softmax, argmax -> prb/seg ---
// r20 change: 300 blocks x 64 thr (one wave/block, ~every CU gets work) vs
// r18's 75x256 which left 181 CUs idle. Per-thread work identical.
__global__ __launch_bounds__(64) void head_kernel(const float* __restrict__ wo,
                                                  const float* __restrict__ bo,
                                                  float* __restrict__ ws) {
    __shared__ float swo[NK * 64];
    __shared__ float sbo[NK];
    for (int i = threadIdx.x; i < NK * 64; i += 64) swo[i] = wo[i];
    if (threadIdx.x < NK) sbo[threadIdx.x] = bo[threadIdx.x];
    __syncthreads();

    int p  = blockIdx.x * 64 + threadIdx.x;    // 0..19199
    int b  = p / P1;
    int pb = p % P1;
    int y  = pb / W1p, x = pb % W1p;
    int qp = (y >> 1) * W2p + (x >> 1);
    const float* c1p = ws + WS_C1 + ((size_t)b * P1 + pb) * 64;
    const float* f2p = ws + WS_F2 + ((size_t)b * P2 + qp) * 64;

    float ok[NK];
#pragma unroll
    for (int k = 0; k < NK; ++k) ok[k] = sbo[k];
#pragma unroll
    for (int o4 = 0; o4 < 16; ++o4) {
        float4 c1q = *(const float4*)(c1p + o4 * 4);
        float4 f2q = *(const float4*)(f2p + o4 * 4);
        float co[4] = { c1q.x + f2q.x, c1q.y + f2q.y, c1q.z + f2q.z, c1q.w + f2q.w };
#pragma unroll
        for (int j = 0; j < 4; ++j) {
            int o = o4 * 4 + j;
#pragma unroll
            for (int k = 0; k < NK; ++k) ok[k] = fmaf(co[j], swo[k * 64 + o], ok[k]);
        }
    }
    float m = 0.f;
#pragma unroll
    for (int k = 0; k < NK; ++k) {
        ok[k] = ok[k] > 0.f ? ok[k] : 0.f;          // relu(out)
        if (ok[k] > m) m = ok[k];
    }
    float e[NK], sum = 0.f;
#pragma unroll
    for (int k = 0; k < NK; ++k) { e[k] = expf(ok[k] - m); sum += e[k]; }
    float inv = 1.f / sum;
    int arg = 0; float best = ok[0];
#pragma unroll
    for (int k = 1; k < NK; ++k) { if (ok[k] > best) { best = ok[k]; arg = k; } }

    float* pr = ws + WS_PRB + (size_t)p * 12;
#pragma unroll
    for (int k = 0; k < NK; ++k) pr[k] = e[k] * inv;
    pr[11] = (float)arg;
    ((int*)(ws + WS_SEG))[p] = arg;
}

// ---------------- upsample 8x: pure streaming replicate-store ----------------
__global__ __launch_bounds__(256) void upsample_kernel(const float* __restrict__ ws,
                                                       float* __restrict__ out) {
    const float* prb = ws + WS_PRB;
    unsigned total4 = (unsigned)((SEG_OFF + (size_t)NB * PLANE) / 4);  // 3,686,400
    unsigned step = gridDim.x * 256;
    for (unsigned i4 = blockIdx.x * 256 + threadIdx.x; i4 < total4; i4 += step) {
        unsigned f = i4 * 4;
        float v;
        if (f < (unsigned)SEG_OFF) {
            unsigned plane = f / (unsigned)PLANE;      // 0..43
            unsigned r = f - plane * (unsigned)PLANE;
            unsigned b = plane / NK, k = plane - b * NK;
            unsigned y = r / WOp, x = r - y * WOp;
            unsigned p = b * P1 + (y >> 3) * W1p + (x >> 3);
            v = prb[p * 12 + k];
        } else {
            unsigned g = f - (unsigned)SEG_OFF;
            unsigned b = g / (unsigned)PLANE;
            unsigned r = g - b * (unsigned)PLANE;
            unsigned y = r / WOp, x = r - y * WOp;
            unsigned p = b * P1 + (y >> 3) * W1p + (x >> 3);
            v = prb[p * 12 + 11];
        }
        *(float4*)(out + f) = make_float4(v, v, v, v);
    }
}

// ---------------- bbox: per-(batch,class) min/max/count over 60x80 seg ------
__global__ __launch_bounds__(256) void bbx_kernel(const float* __restrict__ ws,
                                                  float* __restrict__ out) {
    __shared__ int cnt[10], xmn[10], xmx[10], ymn[10], ymx[10];
    int b = blockIdx.x;
    int t = threadIdx.x;
    if (t < 10) { cnt[t] = 0; xmn[t] = 1 << 30; xmx[t] = -1; ymn[t] = 1 << 30; ymx[t] = -1; }
    __syncthreads();
    const int* seg = (const int*)(ws + WS_SEG) + b * P1;
    for (int p = t; p < P1; p += 256) {
        int s = seg[p];
        if (s >= 1 && s <= 9) {
            int y = p / W1p, x = p % W1p;
            atomicAdd(&cnt[s], 1);
            atomicMin(&xmn[s], x); atomicMax(&xmx[s], x);
            atomicMin(&ymn[s], y); atomicMax(&ymx[s], y);
        }
    }
    __syncthreads();
    if (t < 9) {
        int c = t + 1;
        bool valid = cnt[c] * 64 >= 500;    // upsampled count = 64*count
        float r[6];
        if (valid) {
            r[0] = (float)b;
            r[1] = (float)(xmn[c] * 8);
            r[2] = (float)(ymn[c] * 8);
            r[3] = (float)(xmx[c] * 8 + 7);
            r[4] = (float)(ymx[c] * 8 + 7);
            r[5] = (float)c;
        } else {
            for (int i = 0; i < 6; ++i) r[i] = -1.f;
        }
        float* row = out + BBX_OFF + (size_t)(b * 9 + t) * 6;
        for (int i = 0; i < 6; ++i) row[i] = r[i];
    }
}

extern "C" void kernel_launch(void* const* d_in, const int* in_sizes, int n_in,
                              void* d_out, int out_size, void* d_ws, size_t ws_size,
                              hipStream_t stream) {
    const float* f1 = (const float*)d_in[0];
    const float* f2 = (const float*)d_in[1];
    const float* w1 = (const float*)d_in[2];
    const float* b1 = (const float*)d_in[3];
    const float* w2 = (const float*)d_in[4];
    const float* b2 = (const float*)d_in[5];
    const float* wo = (const float*)d_in[6];
    const float* bo = (const float*)d_in[7];
    float* ws  = (float*)d_ws;
    float* out = (float*)d_out;

    pack_w<<<128, 256, 0, stream>>>(w1, w2, ws);
    conv_mfma<<<376, 256, 0, stream>>>(f1, f2, b1, b2, ws,
                                       ws + WS_C1, ws + WS_F2);
    head_kernel<<<300, 64, 0, stream>>>(wo, bo, ws);
    upsample_kernel<<<2048, 256, 0, stream>>>(ws, out);
    bbx_kernel<<<NB, 256, 0, stream>>>(ws, out);
}

// Round 21
// 57.511 us; speedup vs baseline: 1.1112x; 1.0047x over previous
//
#include <hip/hip_runtime.h>
#include <math.h>

#define NB   4
#define CIN  512
#define HID  64
#define NK   11     // NUM_CLASSES+1
#define HH1  60
#define W1p  80
#define P1   4800
#define HH2  30
#define W2p  40
#define P2   1200
#define HO   480
#define WOp  640
#define NP1  (NB*P1)    // 19200
#define NP2  (NB*P2)    // 4800
#define PLANE ((size_t)HO*WOp)                  // 307200
#define SEG_OFF ((size_t)NB*NK*PLANE)           // 13,516,800
#define BBX_OFF (SEG_OFF + (size_t)NB*PLANE)    // 14,745,600

// ws layout in floats. Packed bf16 W-fragments: 131072 ushort = 65536 floats.
#define WS_C1  65536                            // 19200*64 = 1,228,800
#define WS_F2  (WS_C1 + NP1*64)                 // 4800*64  =   307,200
#define WS_PRB (WS_F2 + NP2*64)                 // 19200*12 =   230,400
#define WS_SEG (WS_PRB + NP1*12)                // 19200 ints

typedef __attribute__((ext_vector_type(8))) short bf16x8;
typedef __attribute__((ext_vector_type(4))) float f32x4;

// RNE fp32 -> bf16, returns bits, writes residual x - bf16(x)
__device__ __forceinline__ unsigned short bfsplit(float x, float& resid) {
    unsigned u = __float_as_uint(x);
    unsigned t = u + 0x7FFFu + ((u >> 16) & 1u);
    unsigned short h = (unsigned short)(t >> 16);
    resid = x - __uint_as_float((unsigned)h << 16);
    return h;
}

// async global->LDS DMA, 16B per lane: lds dest = uniform base + lane*16
__device__ __forceinline__ void gld16(const void* g, void* l) {
    __builtin_amdgcn_global_load_lds(
        (const __attribute__((address_space(1))) void*)g,
        (__attribute__((address_space(3))) void*)l, 16, 0, 0);
}

// -------- pack weights into chunk-major A-fragment pages, 2-plane split -----
// (identical to r13/r18, end-to-end verified at absmax 3.9e-3)
__global__ __launch_bounds__(256) void pack_w(const float* __restrict__ w1,
                                              const float* __restrict__ w2,
                                              float* __restrict__ ws) {
    int i = blockIdx.x * 256 + threadIdx.x;   // 0..32767
    if (i >= HID * CIN) return;
    int o = i >> 9, c = i & 511;
    int chunk = c >> 6, r = c & 63, ks2 = r >> 5, k = r & 31;
    int lane = (o & 15) + ((k >> 3) << 4);
    int mt = o >> 4;
    int d = ((((chunk * 2 + ks2) * 4 + mt) * 2) * 64 + lane) * 8 + (k & 7);
    unsigned short* q = (unsigned short*)ws;
    float r1;
    unsigned short h = bfsplit(w1[i], r1);
    unsigned short m = bfsplit(r1, r1);
    q[d] = h; q[d + 512] = m;                 // plane stride = 64*8 = 512
    h = bfsplit(w2[i], r1); m = bfsplit(r1, r1);
    q[65536 + d] = h; q[65536 + d + 512] = m;
}

// -------- conv1x1 via MFMA v21: 3-deep counted-vmcnt DMA pipeline -----------
// r18 core + T3/T4: 16 chunks of 32ch. X DMA issued 2 chunks ahead (3 bufs),
// A DMA 1 ahead (2 bufs, L2-hot). Counted vmcnt (8/4), NEVER 0 in steady
// state -- loads span phases instead of draining at each barrier. 48KB LDS
// -> 3 blocks/CU (r18: 80KB -> 2). Accumulation order identical to r18.
// Per-wave per-chunk DMA: 2x dmaX + 2x dmaA. Queue audit (oldest->newest):
// ..., X(c) [iter c-2 top], A(c-1) [c-2 mid], X(c+1) [c-1 top], A(c) [c-1
// mid], X(c+2) [c top], A(c+1) [c mid]. convert(c) needs X(c): 8 newer ->
// vmcnt(8). MFMA(c) needs A(c): 4 newer -> vmcnt(4). Tails adjusted.
__global__ __launch_bounds__(256) void conv_mfma(const float* __restrict__ f1,
                                                 const float* __restrict__ f2,
                                                 const float* __restrict__ b1v,
                                                 const float* __restrict__ b2v,
                                                 const float* __restrict__ wsbase,
                                                 float* __restrict__ c1o,
                                                 float* __restrict__ f2o) {
    __shared__ float xraw[3][2048];   // [buf][ch32][px64] fp32, 8KB each
    __shared__ int   alds2[2][2048];  // [buf][A-frag page 32ch], 8KB each
    __shared__ int   xpl[2048];       // B-frags [pt4][plane2][lane64][w4], 8KB
    int t = blockIdx.x;
    const float* X; const float* bias; float* Cout; const int* WPK;
    int P, px0;
    const unsigned short* q = (const unsigned short*)wsbase;
    if (t < 300) {
        int b = t / 75, ti = t % 75;
        px0 = ti * 64;
        X = f1 + (size_t)b * CIN * P1;  P = P1;  bias = b1v;
        WPK = (const int*)q;
        Cout = c1o + (size_t)b * P1 * 64;
    } else {
        int u = t - 300; int b = u / 19, ti = u % 19;
        px0 = ti * 64; if (px0 > P2 - 64) px0 = P2 - 64;  // tail overlap benign
        X = f2 + (size_t)b * CIN * P2;  P = P2;  bias = b2v;
        WPK = (const int*)(q + 65536);
        Cout = f2o + (size_t)b * P2 * 64;
    }
    int tid  = threadIdx.x;
    int lane = tid & 63;
    int wv   = tid >> 6;              // staging pt AND compute mt
    int pcol = lane & 15, kgrp = lane >> 4;

    // load bias BEFORE the DMA pipeline so it can't interleave into the queue
    int r4 = (lane >> 4) * 4;
    float4 bb = *(const float4*)(bias + wv * 16 + r4);
    __builtin_amdgcn_sched_barrier(0);

    // DMA one 32-ch chunk of X: 8 insts/block (2/wave), 1KB each
    auto dmaX = [&](int cc, int buf) {
#pragma unroll
        for (int qq = 0; qq < 2; ++qq) {
            int k = wv * 2 + qq;       // 0..7, covers ch 4k..4k+3
            const float* g = X + (size_t)(cc * 32 + k * 4 + (lane >> 4)) * P
                           + px0 + (lane & 15) * 4;
            gld16(g, (void*)&xraw[buf][k * 256]);
        }
    };
    // DMA one 32-ch A page (8KB, linear, already fragment-ordered)
    auto dmaA = [&](int cc, int buf) {
#pragma unroll
        for (int qq = 0; qq < 2; ++qq) {
            int k = wv * 2 + qq;
            const int* g = WPK + cc * 2048 + k * 256 + lane * 4;
            gld16(g, (void*)&alds2[buf][k * 256]);
        }
    };
    // fp32 -> 2-plane bf16 B-frags (thread owns px wv*16+pcol, chs kgrp*8+j)
    auto convert = [&](int buf) {
        int pxl = wv * 16 + pcol;
        int hh[8], mm[8];
#pragma unroll
        for (int j = 0; j < 8; ++j) {
            float x = xraw[buf][(kgrp * 8 + j) * 64 + pxl];
            float r;
            unsigned short h = bfsplit(x, r);
            unsigned short m = bfsplit(r, r);
            hh[j] = h; mm[j] = m;
        }
        int4 H, M;
        ((int*)&H)[0] = hh[0] | (hh[1] << 16); ((int*)&H)[1] = hh[2] | (hh[3] << 16);
        ((int*)&H)[2] = hh[4] | (hh[5] << 16); ((int*)&H)[3] = hh[6] | (hh[7] << 16);
        ((int*)&M)[0] = mm[0] | (mm[1] << 16); ((int*)&M)[1] = mm[2] | (mm[3] << 16);
        ((int*)&M)[2] = mm[4] | (mm[5] << 16); ((int*)&M)[3] = mm[6] | (mm[7] << 16);
        int pg = (wv * 2) * 256 + lane * 4;
        *(int4*)&xpl[pg]       = H;
        *(int4*)&xpl[pg + 256] = M;
    };

    union FU { int4 q; bf16x8 v; };
    f32x4 acc[4];
#pragma unroll
    for (int st = 0; st < 4; ++st) acc[st] = (f32x4){0.f, 0.f, 0.f, 0.f};

    // prologue: X(0), X(1), A(0) — order matters for the vmcnt audit
    dmaX(0, 0); dmaX(1, 1); dmaA(0, 0);

    for (int c = 0; c < 16; ++c) {
        if (c + 2 < 16) dmaX(c + 2, (c + 2) % 3);
        // wait: own X(c) landed (counted; newer DMAs stay in flight)
        if (c == 0 || c == 14) asm volatile("s_waitcnt vmcnt(6)" ::: "memory");
        else if (c == 15)      asm volatile("s_waitcnt vmcnt(4)" ::: "memory");
        else                   asm volatile("s_waitcnt vmcnt(8)" ::: "memory");
        __builtin_amdgcn_s_barrier();          // all waves' X(c) landed
        __builtin_amdgcn_sched_barrier(0);
        if (c + 1 < 16) dmaA(c + 1, (c + 1) & 1);  // safe: all MFMA(c-1) done
        convert(c % 3);
        // wait: xpl writes retired + own A(c) landed
        if (c <= 13)      asm volatile("s_waitcnt vmcnt(4) lgkmcnt(0)" ::: "memory");
        else if (c == 14) asm volatile("s_waitcnt vmcnt(2) lgkmcnt(0)" ::: "memory");
        else              asm volatile("s_waitcnt vmcnt(0) lgkmcnt(0)" ::: "memory");
        __builtin_amdgcn_s_barrier();          // xpl + A(c) visible to all
        __builtin_amdgcn_sched_barrier(0);
        {
            FU Ah, Am;
            int cur2 = c & 1;
            int pa = (wv * 2) * 256 + lane * 4;
            Ah.q = *(const int4*)&alds2[cur2][pa];
            Am.q = *(const int4*)&alds2[cur2][pa + 256];
#pragma unroll
            for (int st = 0; st < 4; ++st) {
                FU Bh, Bm;
                int pb = (st * 2) * 256 + lane * 4;
                Bh.q = *(const int4*)&xpl[pb];
                Bm.q = *(const int4*)&xpl[pb + 256];
                acc[st] = __builtin_amdgcn_mfma_f32_16x16x32_bf16(Ah.v, Bh.v, acc[st], 0, 0, 0);
                acc[st] = __builtin_amdgcn_mfma_f32_16x16x32_bf16(Ah.v, Bm.v, acc[st], 0, 0, 0);
                acc[st] = __builtin_amdgcn_mfma_f32_16x16x32_bf16(Am.v, Bh.v, acc[st], 0, 0, 0);
                acc[st] = __builtin_amdgcn_mfma_f32_16x16x32_bf16(Am.v, Bm.v, acc[st], 0, 0, 0);
            }
        }
        // no end barrier: next iter's vmcnt+barrier covers xpl/xraw/alds WAR
    }

    // epilogue: C/D layout col=lane&15 (px-in-st), row=(lane>>4)*4+reg
#pragma unroll
    for (int st = 0; st < 4; ++st) {
        int px = px0 + st * 16 + pcol;
        float a0 = acc[st][0] + bb.x;
        float a1 = acc[st][1] + bb.y;
        float a2 = acc[st][2] + bb.z;
        float a3 = acc[st][3] + bb.w;
        *(float4*)(Cout + (size_t)px * 64 + wv * 16 + r4) =
            make_float4(a0 > 0.f ? a0 : 0.f, a1 > 0.f ? a1 : 0.f,
                        a2 > 0.f ? a2 : 0.f, a3 > 0.f ? a3 : 0.f);
    }
}

// ---------------- head: add feat2-up, wo conv, softmax, argmax -> prb/seg ---
// (r18 form: 75 blocks x 256 thr — best-measured config)
__global__ __launch_bounds__(256) void head_kernel(const float* __restrict__ wo,
                                                   const float* __restrict__ bo,
                                                   float* __restrict__ ws) {
    __shared__ float swo[NK * 64];
    __shared__ float sbo[NK];
    for (int i = threadIdx.x; i < NK * 64; i += 256) swo[i] = wo[i];
    if (threadIdx.x < NK) sbo[threadIdx.x] = bo[threadIdx.x];
    __syncthreads();

    int p  = blockIdx.x * 256 + threadIdx.x;   // 0..19199
    int b  = p / P1;
    int pb = p % P1;
    int y  = pb / W1p, x = pb % W1p;
    int qp = (y >> 1) * W2p + (x >> 1);
    const float* c1p = ws + WS_C1 + ((size_t)b * P1 + pb) * 64;
    const float* f2p = ws + WS_F2 + ((size_t)b * P2 + qp) * 64;

    float ok[NK];
#pragma unroll
    for (int k = 0; k < NK; ++k) ok[k] = sbo[k];
#pragma unroll
    for (int o4 = 0; o4 < 16; ++o4) {
        float4 c1q = *(const float4*)(c1p + o4 * 4);
        float4 f2q = *(const float4*)(f2p + o4 * 4);
        float co[4] = { c1q.x + f2q.x, c1q.y + f2q.y, c1q.z + f2q.z, c1q.w + f2q.w };
#pragma unroll
        for (int j = 0; j < 4; ++j) {
            int o = o4 * 4 + j;
#pragma unroll
            for (int k = 0; k < NK; ++k) ok[k] = fmaf(co[j], swo[k * 64 + o], ok[k]);
        }
    }
    float m = 0.f;
#pragma unroll
    for (int k = 0; k < NK; ++k) {
        ok[k] = ok[k] > 0.f ? ok[k] : 0.f;          // relu(out)
        if (ok[k] > m) m = ok[k];
    }
    float e[NK], sum = 0.f;
#pragma unroll
    for (int k = 0; k < NK; ++k) { e[k] = expf(ok[k] - m); sum += e[k]; }
    float inv = 1.f / sum;
    int arg = 0; float best = ok[0];
#pragma unroll
    for (int k = 1; k < NK; ++k) { if (ok[k] > best) { best = ok[k]; arg = k; } }

    float* pr = ws + WS_PRB + (size_t)p * 12;
#pragma unroll
    for (int k = 0; k < NK; ++k) pr[k] = e[k] * inv;
    pr[11] = (float)arg;
    ((int*)(ws + WS_SEG))[p] = arg;
}

// ---------------- upsample 8x: pure streaming replicate-store ----------------
__global__ __launch_bounds__(256) void upsample_kernel(const float* __restrict__ ws,
                                                       float* __restrict__ out) {
    const float* prb = ws + WS_PRB;
    unsigned total4 = (unsigned)((SEG_OFF + (size_t)NB * PLANE) / 4);  // 3,686,400
    unsigned step = gridDim.x * 256;
    for (unsigned i4 = blockIdx.x * 256 + threadIdx.x; i4 < total4; i4 += step) {
        unsigned f = i4 * 4;
        float v;
        if (f < (unsigned)SEG_OFF) {
            unsigned plane = f / (unsigned)PLANE;      // 0..43
            unsigned r = f - plane * (unsigned)PLANE;
            unsigned b = plane / NK, k = plane - b * NK;
            unsigned y = r / WOp, x = r - y * WOp;
            unsigned p = b * P1 + (y >> 3) * W1p + (x >> 3);
            v = prb[p * 12 + k];
        } else {
            unsigned g = f - (unsigned)SEG_OFF;
            unsigned b = g / (unsigned)PLANE;
            unsigned r = g - b * (unsigned)PLANE;
            unsigned y = r / WOp, x = r - y * WOp;
            unsigned p = b * P1 + (y >> 3) * W1p + (x >> 3);
            v = prb[p * 12 + 11];
        }
        *(float4*)(out + f) = make_float4(v, v, v, v);
    }
}

// ---------------- bbox: per-(batch,class) min/max/count over 60x80 seg ------
__global__ __launch_bounds__(256) void bbx_kernel(const float* __restrict__ ws,
                                                  float* __restrict__ out) {
    __shared__ int cnt[10], xmn[10], xmx[10], ymn[10], ymx[10];
    int b = blockIdx.x;
    int t = threadIdx.x;
    if (t < 10) { cnt[t] = 0; xmn[t] = 1 << 30; xmx[t] = -1; ymn[t] = 1 << 30; ymx[t] = -1; }
    __syncthreads();
    const int* seg = (const int*)(ws + WS_SEG) + b * P1;
    for (int p = t; p < P1; p += 256) {
        int s = seg[p];
        if (s >= 1 && s <= 9) {
            int y = p / W1p, x = p % W1p;
            atomicAdd(&cnt[s], 1);
            atomicMin(&xmn[s], x); atomicMax(&xmx[s], x);
            atomicMin(&ymn[s], y); atomicMax(&ymx[s], y);
        }
    }
    __syncthreads();
    if (t < 9) {
        int c = t + 1;
        bool valid = cnt[c] * 64 >= 500;    // upsampled count = 64*count
        float r[6];
        if (valid) {
            r[0] = (float)b;
            r[1] = (float)(xmn[c] * 8);
            r[2] = (float)(ymn[c] * 8);
            r[3] = (float)(xmx[c] * 8 + 7);
            r[4] = (float)(ymx[c] * 8 + 7);
            r[5] = (float)c;
        } else {
            for (int i = 0; i < 6; ++i) r[i] = -1.f;
        }
        float* row = out + BBX_OFF + (size_t)(b * 9 + t) * 6;
        for (int i = 0; i < 6; ++i) row[i] = r[i];
    }
}

extern "C" void kernel_launch(void* const* d_in, const int* in_sizes, int n_in,
                              void* d_out, int out_size, void* d_ws, size_t ws_size,
                              hipStream_t stream) {
    const float* f1 = (const float*)d_in[0];
    const float* f2 = (const float*)d_in[1];
    const float* w1 = (const float*)d_in[2];
    const float* b1 = (const float*)d_in[3];
    const float* w2 = (const float*)d_in[4];
    const float* b2 = (const float*)d_in[5];
    const float* wo = (const float*)d_in[6];
    const float* bo = (const float*)d_in[7];
    float* ws  = (float*)d_ws;
    float* out = (float*)d_out;

    pack_w<<<128, 256, 0, stream>>>(w1, w2, ws);
    conv_mfma<<<376, 256, 0, stream>>>(f1, f2, b1, b2, ws,
                                       ws + WS_C1, ws + WS_F2);
    head_kernel<<<75, 256, 0, stream>>>(wo, bo, ws);
    upsample_kernel<<<2048, 256, 0, stream>>>(ws, out);
    bbx_kernel<<<NB, 256, 0, stream>>>(ws, out);
}